// Round 4
// baseline (423.123 us; speedup 1.0000x reference)
//
#include <hip/hip_runtime.h>
#include <stdint.h>

// GraphConvLayer: out[n,:] = W[type[n]] @ (A @ x)[n,:]
// N=16384, D=128, T=8.  A is 1 GiB f32 read exactly once -> HBM floor ~163us.
// Round 4: BM=32, 256 threads, grid=512 -> 2 blocks/CU so cross-block overlap
// fills barrier/latency bubbles (round 3 was 1 block/CU, ~2x floor).
// Same pipeline as round 3: 4-deep named-register prefetch (A and X),
// double-buffered LDS, lgkm-only barriers (VMEM prefetch never drained).

#define N_NODES 16384
#define DIM     128
#define NTYPES  8
#define BM      32
#define BK      64
#define NIT     (N_NODES / BK)   // 256

typedef float f32x4 __attribute__((ext_vector_type(4)));
typedef short s16x8 __attribute__((ext_vector_type(8)));

__device__ __attribute__((aligned(16))) unsigned short g_xT[DIM * N_NODES];      // [d][n], 4 MiB
__device__ __attribute__((aligned(16))) unsigned short g_Wb[NTYPES * DIM * DIM]; // [t][o][d], 256 KiB

__device__ __forceinline__ unsigned int f2b(float f) {
    unsigned int u = __float_as_uint(f);
    u += 0x7FFFu + ((u >> 16) & 1u);   // round-to-nearest-even
    return u >> 16;
}
#define BF_LO(u) __uint_as_float((unsigned int)(u) << 16)
#define BF_HI(u) __uint_as_float((unsigned int)(u) & 0xFFFF0000u)

// ---------------- fused prep kernel ----------------
// blocks 0..63: xT transpose+convert; blocks 64..95: W convert.

__global__ void prep_all(const float* __restrict__ x, const float* __restrict__ w) {
    const int tid = threadIdx.x;
    if (blockIdx.x < 64) {
        int n = blockIdx.x * 256 + tid;
        const float* row = x + (size_t)n * DIM;
#pragma unroll
        for (int d0 = 0; d0 < DIM; d0 += 4) {
            float4 v = *(const float4*)(row + d0);
            g_xT[(d0 + 0) * N_NODES + n] = (unsigned short)f2b(v.x);
            g_xT[(d0 + 1) * N_NODES + n] = (unsigned short)f2b(v.y);
            g_xT[(d0 + 2) * N_NODES + n] = (unsigned short)f2b(v.z);
            g_xT[(d0 + 3) * N_NODES + n] = (unsigned short)f2b(v.w);
        }
    } else {
        int base = ((blockIdx.x - 64) * 256 + tid) * 16;
#pragma unroll
        for (int j = 0; j < 4; ++j) {
            float4 v = *(const float4*)(w + base + j * 4);
            ushort4 o;
            o.x = (unsigned short)f2b(v.x); o.y = (unsigned short)f2b(v.y);
            o.z = (unsigned short)f2b(v.z); o.w = (unsigned short)f2b(v.w);
            *(ushort4*)(g_Wb + base + j * 4) = o;
        }
    }
}

// ---------------- main fused kernel ----------------

#define ASTRIDE 72                           // 64 + 8 pad shorts (144 B rows)
#define ABYTES  (BM * ASTRIDE * 2)           // 4608 B per A buffer
#define XBYTES  (DIM * ASTRIDE * 2)          // 18432 B per X buffer

// barrier with LDS-visibility only: VMEM prefetch stays in flight
#define BAR() asm volatile("s_waitcnt lgkmcnt(0)\n\ts_barrier" ::: "memory")

// load tile t: A = 2 float4 (one 32B row-chunk), X = 4 uint4 (one 64B row-chunk)
#define LOADG(t, rA0, rA1, rX0, rX1, rX2, rX3) do {              \
    rA0 = *(const float4*)(aPtr + (size_t)(t) * BK);             \
    rA1 = *(const float4*)(aPtr + (size_t)(t) * BK + 4);         \
    rX0 = *(const uint4*)(xPtr + (size_t)(t) * BK);              \
    rX1 = *(const uint4*)(xPtr + (size_t)(t) * BK + 8);          \
    rX2 = *(const uint4*)(xPtr + (size_t)(t) * BK + 16);         \
    rX3 = *(const uint4*)(xPtr + (size_t)(t) * BK + 24);         \
} while (0)

#define STORE(As_, Xs_, rA0, rA1, rX0, rX1, rX2, rX3) do {       \
    uint4 pa;                                                    \
    pa.x = f2b(rA0.x) | (f2b(rA0.y) << 16);                      \
    pa.y = f2b(rA0.z) | (f2b(rA0.w) << 16);                      \
    pa.z = f2b(rA1.x) | (f2b(rA1.y) << 16);                      \
    pa.w = f2b(rA1.z) | (f2b(rA1.w) << 16);                      \
    *(uint4*)((As_) + ar * ASTRIDE + ac) = pa;                   \
    *(uint4*)((Xs_) + xd * ASTRIDE + xk) = rX0;                  \
    *(uint4*)((Xs_) + xd * ASTRIDE + xk + 8) = rX1;              \
    *(uint4*)((Xs_) + xd * ASTRIDE + xk + 16) = rX2;             \
    *(uint4*)((Xs_) + xd * ASTRIDE + xk + 24) = rX3;             \
} while (0)

#define MFMA4(As_, Xs_, kk) do {                                                      \
    s16x8 a_  = *(const s16x8*)((As_) + (mrow + (lane & 15)) * ASTRIDE + (kk));       \
    s16x8 b0_ = *(const s16x8*)((Xs_) + (ncol +  0 + (lane & 15)) * ASTRIDE + (kk));  \
    s16x8 b1_ = *(const s16x8*)((Xs_) + (ncol + 16 + (lane & 15)) * ASTRIDE + (kk));  \
    s16x8 b2_ = *(const s16x8*)((Xs_) + (ncol + 32 + (lane & 15)) * ASTRIDE + (kk));  \
    s16x8 b3_ = *(const s16x8*)((Xs_) + (ncol + 48 + (lane & 15)) * ASTRIDE + (kk));  \
    asm("v_mfma_f32_16x16x32_bf16 %0, %1, %2, %0" : "+v"(acc0) : "v"(a_), "v"(b0_));  \
    asm("v_mfma_f32_16x16x32_bf16 %0, %1, %2, %0" : "+v"(acc1) : "v"(a_), "v"(b1_));  \
    asm("v_mfma_f32_16x16x32_bf16 %0, %1, %2, %0" : "+v"(acc2) : "v"(a_), "v"(b2_));  \
    asm("v_mfma_f32_16x16x32_bf16 %0, %1, %2, %0" : "+v"(acc3) : "v"(a_), "v"(b3_));  \
} while (0)

#define COMPUTE(As_, Xs_) do {           \
    const int kkc = (lane >> 4) * 8;     \
    MFMA4(As_, Xs_, kkc);                \
    MFMA4(As_, Xs_, kkc + 32);           \
} while (0)

__global__ __launch_bounds__(256, 2) void gconv_main(
    const float* __restrict__ adj,
    const int* __restrict__ types,
    float* __restrict__ out)
{
    __shared__ __align__(16) unsigned char lds[2 * ABYTES + 2 * XBYTES]; // 46080 B; reused as agg f32
    unsigned short* As0 = (unsigned short*)lds;
    unsigned short* As1 = As0 + BM * ASTRIDE;
    unsigned short* Xs0 = As0 + 2 * BM * ASTRIDE;
    unsigned short* Xs1 = Xs0 + DIM * ASTRIDE;

    const int tid  = threadIdx.x;
    const int w    = tid >> 6;          // 0..3
    const int lane = tid & 63;
    const int m0   = blockIdx.x * BM;

    const int mrow = (w & 1) * 16;      // wave's 16 output rows (of 32)
    const int ncol = (w >> 1) * 64;     // wave's 64 output cols (of 128)

    f32x4 acc0 = {}, acc1 = {}, acc2 = {}, acc3 = {};

    // staging index math (256 threads per tile)
    const int ar = tid >> 3;                  // A row 0..31
    const int ac = (tid & 7) * 8;             // 8-float chunk in row (shorts offset after cvt)
    const int xd = tid >> 1;                  // X row (d) 0..127
    const int xk = (tid & 1) * 32;            // 32-short chunk in row
    const float* aPtr = adj + (size_t)(m0 + ar) * N_NODES + ac;
    const unsigned short* xPtr = g_xT + (size_t)xd * N_NODES + xk;

    // 4 named register parities (NO arrays -> NO scratch, rule #20)
    float4 aA0, aB0, aA1, aB1, aA2, aB2, aA3, aB3;
    uint4  x00, x01, x02, x03, x10, x11, x12, x13,
           x20, x21, x22, x23, x30, x31, x32, x33;

    // ---- prologue: 4 tiles in flight, tile 0 staged ----
    LOADG(0, aA0, aB0, x00, x01, x02, x03);
    LOADG(1, aA1, aB1, x10, x11, x12, x13);
    LOADG(2, aA2, aB2, x20, x21, x22, x23);
    LOADG(3, aA3, aB3, x30, x31, x32, x33);
    STORE(As0, Xs0, aA0, aB0, x00, x01, x02, x03);
    BAR();

    // ---- steady state: 4 phases/iter; tile t's STORE is 3 phases after
    // its LOADG issued (~2000 cy HBM-latency cover). ----
    for (int i = 0; i < 63; ++i) {
        const int t0 = 4 * i;
        LOADG(t0 + 4, aA0, aB0, x00, x01, x02, x03);
        COMPUTE(As0, Xs0);
        STORE(As1, Xs1, aA1, aB1, x10, x11, x12, x13);
        BAR();
        LOADG(t0 + 5, aA1, aB1, x10, x11, x12, x13);
        COMPUTE(As1, Xs1);
        STORE(As0, Xs0, aA2, aB2, x20, x21, x22, x23);
        BAR();
        LOADG(t0 + 6, aA2, aB2, x20, x21, x22, x23);
        COMPUTE(As0, Xs0);
        STORE(As1, Xs1, aA3, aB3, x30, x31, x32, x33);
        BAR();
        LOADG(t0 + 7, aA3, aB3, x30, x31, x32, x33);
        COMPUTE(As1, Xs1);
        STORE(As0, Xs0, aA0, aB0, x00, x01, x02, x03);
        BAR();
    }
    // ---- tail: tiles 252..255, no more loads ----
    COMPUTE(As0, Xs0);
    STORE(As1, Xs1, aA1, aB1, x10, x11, x12, x13);
    BAR();
    COMPUTE(As1, Xs1);
    STORE(As0, Xs0, aA2, aB2, x20, x21, x22, x23);
    BAR();
    COMPUTE(As0, Xs0);
    STORE(As1, Xs1, aA3, aB3, x30, x31, x32, x33);
    BAR();
    COMPUTE(As1, Xs1);
    __syncthreads();   // full drain before reusing LDS as agg

    // ---- epilogue: acc -> LDS agg (f32), then per-row W[type] dots ----
    float* agg = (float*)lds;   // [32][132] = 16896 B
#pragma unroll
    for (int r = 0; r < 4; ++r) {
        const int gr = (mrow + (lane >> 4) * 4 + r) * 132 + ncol + (lane & 15);
        agg[gr +  0] = acc0[r];
        agg[gr + 16] = acc1[r];
        agg[gr + 32] = acc2[r];
        agg[gr + 48] = acc3[r];
    }
    __syncthreads();

    const int rbase = w * 8;   // 8 rows per wave
    for (int rr = 0; rr < 8; ++rr) {
        const int rw = rbase + rr;
        const int nn = m0 + rw;
        const int ty = types[nn];                      // wave-uniform
        const unsigned short* Wt = g_Wb + ty * (DIM * DIM);
        const int o0 = lane * 2;
        const float* aggRow = agg + rw * 132;
        float s0 = 0.f, s1 = 0.f;
#pragma unroll
        for (int d0 = 0; d0 < DIM; d0 += 8) {
            float4 ga = *(const float4*)(aggRow + d0);
            float4 gb = *(const float4*)(aggRow + d0 + 4);
            uint4 wa = *(const uint4*)(Wt + o0 * DIM + d0);
            uint4 wb = *(const uint4*)(Wt + (o0 + 1) * DIM + d0);
            s0 += ga.x * BF_LO(wa.x) + ga.y * BF_HI(wa.x) + ga.z * BF_LO(wa.y) + ga.w * BF_HI(wa.y);
            s0 += gb.x * BF_LO(wa.z) + gb.y * BF_HI(wa.z) + gb.z * BF_LO(wa.w) + gb.w * BF_HI(wa.w);
            s1 += ga.x * BF_LO(wb.x) + ga.y * BF_HI(wb.x) + ga.z * BF_LO(wb.y) + ga.w * BF_HI(wb.y);
            s1 += gb.x * BF_LO(wb.z) + gb.y * BF_HI(wb.z) + gb.z * BF_LO(wb.w) + gb.w * BF_HI(wb.w);
        }
        float2 res; res.x = s0; res.y = s1;
        *(float2*)(out + (size_t)nn * DIM + o0) = res;
    }
}

// ---------------- launch ----------------

extern "C" void kernel_launch(void* const* d_in, const int* in_sizes, int n_in,
                              void* d_out, int out_size, void* d_ws, size_t ws_size,
                              hipStream_t stream) {
    const float* x     = (const float*)d_in[0];
    const int*   types = (const int*)d_in[1];
    const float* adj   = (const float*)d_in[2];
    const float* wt    = (const float*)d_in[3];
    float* out = (float*)d_out;

    hipLaunchKernelGGL(prep_all, dim3(96), dim3(256), 0, stream, x, wt);
    hipLaunchKernelGGL(gconv_main, dim3(N_NODES / BM), dim3(256), 0, stream, adj, types, out);
}